// Round 16
// baseline (13160.654 us; speedup 1.0000x reference)
//
#include <hip/hip_runtime.h>
#include <math.h>

// Problem constants
#define B_ 256
#define S_ 128
#define F_ 128
#define H_ 512
#define A_ 512
#define C_ 128
#define HSLICE (H_ * B_)

#define DOT4(va, vb) ((va).x*(vb).x + (va).y*(vb).y + (va).z*(vb).z + (va).w*(vb).w)

// ---------------------------------------------------------------------------
// deep-prefetch k-major dot: 32-float double-buffer window.
// acc slots 0..3 = r0,r1,z0,z1 ; acc[NH],acc[NH+1] = n0,n1 partial.
// ---------------------------------------------------------------------------
template<int NH>
__device__ __forceinline__ void acc_chunks(const float* __restrict__ src,
                                           const float* __restrict__ W6k,
                                           int nk, int b, float* __restrict__ acc)
{
    float a0[32], a1[32];
#pragma unroll
    for (int j = 0; j < 32; ++j) a0[j] = src[(size_t)j * B_ + b];
    for (int kc = 0; kc < nk; kc += 32) {
        if (kc + 32 < nk) {
#pragma unroll
            for (int j = 0; j < 32; ++j)
                a1[j] = src[(size_t)(kc + 32 + j) * B_ + b];
        }
        const float* Wr = W6k + (size_t)kc * 6;
#pragma unroll
        for (int j = 0; j < 32; ++j) {
            float av = a0[j];
            acc[0]    = fmaf(av, Wr[j * 6 + 0], acc[0]);
            acc[1]    = fmaf(av, Wr[j * 6 + 1], acc[1]);
            acc[2]    = fmaf(av, Wr[j * 6 + 2], acc[2]);
            acc[3]    = fmaf(av, Wr[j * 6 + 3], acc[3]);
            acc[NH]   = fmaf(av, Wr[j * 6 + 4], acc[NH]);
            acc[NH+1] = fmaf(av, Wr[j * 6 + 5], acc[NH + 1]);
        }
#pragma unroll
        for (int j = 0; j < 32; ++j) a0[j] = a1[j];
    }
}

// per-lane x-row (128 contiguous floats) against W6 x-part; n -> slots 4,5
__device__ __forceinline__ void acc_xrow(const float4* __restrict__ xr,
                                         const float* __restrict__ W6k,
                                         float* __restrict__ acc)
{
    float4 c0[8], c1[8];
#pragma unroll
    for (int j = 0; j < 8; ++j) c0[j] = xr[j];
    for (int q = 0; q < 32; q += 8) {
        if (q + 8 < 32) {
#pragma unroll
            for (int j = 0; j < 8; ++j) c1[j] = xr[q + 8 + j];
        }
#pragma unroll
        for (int j = 0; j < 8; ++j) {
            const float* Wr = W6k + (size_t)((q + j) * 4) * 6;
            float e0 = c0[j].x, e1 = c0[j].y, e2 = c0[j].z, e3 = c0[j].w;
#pragma unroll
            for (int t2 = 0; t2 < 4; ++t2) {
                float av = (t2 == 0) ? e0 : (t2 == 1) ? e1 : (t2 == 2) ? e2 : e3;
                acc[0] = fmaf(av, Wr[t2 * 6 + 0], acc[0]);
                acc[1] = fmaf(av, Wr[t2 * 6 + 1], acc[1]);
                acc[2] = fmaf(av, Wr[t2 * 6 + 2], acc[2]);
                acc[3] = fmaf(av, Wr[t2 * 6 + 3], acc[3]);
                acc[4] = fmaf(av, Wr[t2 * 6 + 4], acc[4]);
                acc[5] = fmaf(av, Wr[t2 * 6 + 5], acc[5]);
            }
        }
#pragma unroll
        for (int j = 0; j < 8; ++j) c0[j] = c1[j];
    }
}

// ---------------------------------------------------------------------------
// prep_all: W6e + W6d + w2q packs, xT transpose, biases, h0T zero.
// grid 3840 x 256 (id < 983040).
// ---------------------------------------------------------------------------
__global__ __launch_bounds__(256)
void prep_all(const float* __restrict__ x,
              const float* __restrict__ eWih, const float* __restrict__ eWhh,
              const float* __restrict__ dWih, const float* __restrict__ dWhh,
              const float* __restrict__ ebih, const float* __restrict__ ebhh,
              const float* __restrict__ dbih, const float* __restrict__ dbhh,
              const float* __restrict__ w2,
              float* __restrict__ xT, float* __restrict__ W6e,
              float* __restrict__ W6d, float4* __restrict__ w2q,
              float* __restrict__ bias4e, float* __restrict__ bias4d,
              float* __restrict__ h0T)
{
    int id = blockIdx.x * 256 + threadIdx.x;   // < 983040
    {
        int up = id / 3840;
        int rem = id - up * 3840;
        int k = rem / 6, g = rem - k * 6;
        int row = (g >> 1) * H_ + up * 2 + (g & 1);
        if (k < F_) {
            W6e[id] = eWih[(size_t)row * F_ + k];
            W6d[id] = dWih[(size_t)row * F_ + k];
        } else {
            W6e[id] = eWhh[(size_t)row * H_ + (k - F_)];
            W6d[id] = dWhh[(size_t)row * H_ + (k - F_)];
        }
    }
#pragma unroll
    for (int r = 0; r < 5; ++r) {
        int xid = id + r * 983040;
        if (xid < S_ * F_ * B_) {
            int b2 = xid & 255, f = (xid >> 8) & 127, t = xid >> 15;
            xT[xid] = x[(size_t)b2 * (S_ * F_) + (size_t)t * F_ + f];
        }
    }
    if (id < 128 * 512) {
        int k4 = id >> 9, a = id & 511;
        const float* s = w2 + (size_t)a * H_ + k4 * 4;
        w2q[id] = make_float4(s[0], s[1], s[2], s[3]);
    }
    if (id < H_ * B_) h0T[id] = 0.f;
    if (id < H_) {
        bias4e[id * 4 + 0] = ebih[id] + ebhh[id];
        bias4e[id * 4 + 1] = ebih[H_ + id] + ebhh[H_ + id];
        bias4e[id * 4 + 2] = ebih[2 * H_ + id];
        bias4e[id * 4 + 3] = ebhh[2 * H_ + id];
        bias4d[id * 4 + 0] = dbih[id] + dbhh[id];
        bias4d[id * 4 + 1] = dbih[H_ + id] + dbhh[H_ + id];
        bias4d[id * 4 + 2] = dbih[2 * H_ + id];
        bias4d[id * 4 + 3] = dbhh[2 * H_ + id];
    }
}

// ---------------------------------------------------------------------------
// GRU step: grid 512 = upq(128) x bh(4); 256 threads = 4 waves
// (upl = w&1 selects unit-pair, kw = w>>1 selects k-half).
// Block owns 2 unit-pairs (4 units) x 64 batches: halves per-step L2
// activation traffic vs the 1-pair/block version (same waves/CU).
// x-part: k-major inT (encoder) or per-lane x-row gather via pred (decoder).
// ---------------------------------------------------------------------------
__global__ __launch_bounds__(256)
void gru_step(const float* __restrict__ inT,    // [F][B] k-major or nullptr
              const float* __restrict__ x,      // [B][S][F] or nullptr
              const int*   __restrict__ pred,   // [B] or nullptr
              const float* __restrict__ hinT,   // [H][B]
              const float* __restrict__ W6,     // [256][640][6]
              const float* __restrict__ bias4,  // [512][4]
              float* __restrict__ houtT,        // [H][B]
              float* __restrict__ hB)           // [B][H] or nullptr
{
    __shared__ float accL[2][64][6];
    const int tid = threadIdx.x;
    const int lane = tid & 63;
    const int w = tid >> 6;
    const int upl = w & 1;
    const int kw = w >> 1;
    const int upq = blockIdx.x & 127;
    const int bh = blockIdx.x >> 7;
    const int b = bh * 64 + lane;
    const int up = upq * 2 + upl;
    const float* Wb = W6 + (size_t)up * 3840;
    const int u0 = up * 2, u1 = u0 + 1;

    float acc[8];
#pragma unroll
    for (int g = 0; g < 8; ++g) acc[g] = 0.f;

    float hold0 = 0.f, hold1 = 0.f;
    if (kw == 0) {
        hold0 = hinT[(size_t)u0 * B_ + b];
        hold1 = hinT[(size_t)u1 * B_ + b];
        if (inT) {
            acc_chunks<4>(inT, Wb, F_, b, acc);
        } else if (pred) {
            int pb = pred[b];
            const float4* xr = (const float4*)(x + ((size_t)b * S_ + pb) * F_);
            acc_xrow(xr, Wb, acc);
        }
        acc_chunks<6>(hinT, Wb + F_ * 6, 192, b, acc);
    } else {
        acc_chunks<6>(hinT + (size_t)192 * B_, Wb + 320 * 6, 320, b, acc);
    }

    if (kw == 1) {
        accL[upl][lane][0] = acc[0]; accL[upl][lane][1] = acc[1];
        accL[upl][lane][2] = acc[2]; accL[upl][lane][3] = acc[3];
        accL[upl][lane][4] = acc[6]; accL[upl][lane][5] = acc[7];
    }
    __syncthreads();
    if (kw == 0) {
        const float4 bb0 = *(const float4*)(bias4 + u0 * 4);
        const float4 bb1 = *(const float4*)(bias4 + u1 * 4);
        float rr0 = 1.f / (1.f + expf(-(acc[0] + accL[upl][lane][0] + bb0.x)));
        float rr1 = 1.f / (1.f + expf(-(acc[1] + accL[upl][lane][1] + bb1.x)));
        float zz0 = 1.f / (1.f + expf(-(acc[2] + accL[upl][lane][2] + bb0.y)));
        float zz1 = 1.f / (1.f + expf(-(acc[3] + accL[upl][lane][3] + bb1.y)));
        float hn0 = acc[6] + accL[upl][lane][4] + bb0.w;
        float hn1 = acc[7] + accL[upl][lane][5] + bb1.w;
        float nn0 = tanhf(acc[4] + bb0.z + rr0 * hn0);
        float nn1 = tanhf(acc[5] + bb1.z + rr1 * hn1);
        float h0v = (1.f - zz0) * nn0 + zz0 * hold0;
        float h1v = (1.f - zz1) * nn1 + zz1 * hold1;
        houtT[(size_t)u0 * B_ + b] = h0v;
        houtT[(size_t)u1 * B_ + b] = h1v;
        if (hB) {
            hB[(size_t)b * H_ + u0] = h0v;
            hB[(size_t)b * H_ + u1] = h1v;
        }
    }
}

// ---------------------------------------------------------------------------
// Fused w2 + attention + softmax + argmax + loss + pred publish.
// Block = batch b, 512 threads (8 waves). (round-14, validated)
// ---------------------------------------------------------------------------
__global__ __launch_bounds__(512)
void w2attn_step(const float* __restrict__ hB,    // [B][H]
                 const float4* __restrict__ w2q,  // [128 k4][512 a]
                 const float* __restrict__ v, const int* __restrict__ y,
                 int step, const float* __restrict__ proj,  // [b][s][a]
                 int* __restrict__ predBuf,
                 float* __restrict__ nlogp, float* __restrict__ preds_out)
{
    const int b = blockIdx.x;
    const int tid = threadIdx.x;
    __shared__ float sh[512];
    __shared__ float sq[512];
    __shared__ float sScore[S_], sProb[S_];

    sh[tid] = hB[(size_t)b * H_ + tid];
    __syncthreads();

    {
        float acc = 0.f;
        const float4* wp = w2q + tid;
#pragma unroll 8
        for (int k4 = 0; k4 < 128; ++k4) {
            float4 hv = *(const float4*)&sh[k4 * 4];
            float4 wv4 = wp[(size_t)k4 * 512];
            acc += DOT4(hv, wv4);
        }
        sq[tid] = acc;
    }
    __syncthreads();

    const int wv = tid >> 6, ln = tid & 63;
    float4 q0 = *(const float4*)&sq[ln * 8];
    float4 q1 = *(const float4*)&sq[ln * 8 + 4];
    float4 v0r = *(const float4*)(v + ln * 8);
    float4 v1r = *(const float4*)(v + ln * 8 + 4);
    const float* epb = proj + (size_t)b * (S_ * A_);
    for (int si = 0; si < 16; ++si) {
        int s = si * 8 + wv;
        const float* row = epb + (size_t)s * A_ + ln * 8;
        float4 p0 = *(const float4*)(row);
        float4 p1 = *(const float4*)(row + 4);
        float acc = fmaxf(p0.x + q0.x, 0.f) * v0r.x
                  + fmaxf(p0.y + q0.y, 0.f) * v0r.y
                  + fmaxf(p0.z + q0.z, 0.f) * v0r.z
                  + fmaxf(p0.w + q0.w, 0.f) * v0r.w
                  + fmaxf(p1.x + q1.x, 0.f) * v1r.x
                  + fmaxf(p1.y + q1.y, 0.f) * v1r.y
                  + fmaxf(p1.z + q1.z, 0.f) * v1r.z
                  + fmaxf(p1.w + q1.w, 0.f) * v1r.w;
#pragma unroll
        for (int off = 32; off; off >>= 1) acc += __shfl_down(acc, off);
        if (ln == 0) sScore[s] = acc;
    }
    __syncthreads();

    if (tid < 64) {
        float s0v = sScore[tid], s1v = sScore[tid + 64];
        float m = fmaxf(s0v, s1v);
#pragma unroll
        for (int off = 32; off; off >>= 1) m = fmaxf(m, __shfl_xor(m, off));
        float e0 = expf(s0v - m), e1 = expf(s1v - m);
        float se = e0 + e1;
#pragma unroll
        for (int off = 32; off; off >>= 1) se += __shfl_xor(se, off);
        float p0 = e0 / se, p1 = e1 / se;
        sProb[tid] = p0; sProb[tid + 64] = p1;
        float pm = fmaxf(p0, p1);
#pragma unroll
        for (int off = 32; off; off >>= 1) pm = fmaxf(pm, __shfl_xor(pm, off));
        float t0 = expf(p0 - pm), t1 = expf(p1 - pm);
        float T = t0 + t1;
#pragma unroll
        for (int off = 32; off; off >>= 1) T += __shfl_xor(T, off);
        float bv = p0; int bi2 = tid;
        if (p1 > bv) { bv = p1; bi2 = tid + 64; }
#pragma unroll
        for (int off = 32; off; off >>= 1) {
            float ov = __shfl_xor(bv, off);
            int oi = __shfl_xor(bi2, off);
            if (ov > bv || (ov == bv && oi < bi2)) { bv = ov; bi2 = oi; }
        }
        if (tid == 0) {
            int yy = y[(size_t)b * C_ + step];
            float py = sProb[yy];
            nlogp[(size_t)step * B_ + b] = -(py - pm - logf(T));
            preds_out[(size_t)b * C_ + step] = (float)bi2;
            predBuf[b] = bi2;
        }
    }
}

// ---------------------------------------------------------------------------
// proj[b][s][a] = sum_j encT[s][j][b] * w1[a][j]   (padded sB)
// ---------------------------------------------------------------------------
__global__ __launch_bounds__(256)
void proj_gemm(const float* __restrict__ encT, const float* __restrict__ w1,
               float* __restrict__ proj)
{
    __shared__ float sA[32][128];
    __shared__ float sB[32][132];
    const int tid = threadIdx.x;
    const int s = blockIdx.z;
    const int b0 = blockIdx.y * 128;
    const int a0 = blockIdx.x * 128;
    const int tx = tid & 15, ty = tid >> 4;

    float acc[8][8];
#pragma unroll
    for (int i = 0; i < 8; ++i)
#pragma unroll
        for (int jj = 0; jj < 8; ++jj) acc[i][jj] = 0.f;

    const float* Abase = encT + (size_t)s * HSLICE + b0;
    for (int kc = 0; kc < H_; kc += 32) {
#pragma unroll
        for (int p = 0; p < 16; ++p) {
            int idx = tid + p * 256;
            int kj = idx >> 7, bbb = idx & 127;
            sA[kj][bbb] = Abase[(size_t)(kc + kj) * B_ + bbb];
        }
#pragma unroll
        for (int p = 0; p < 16; ++p) {
            int idx = tid + p * 256;
            int aa = idx >> 5, kj = idx & 31;
            sB[kj][aa] = w1[(size_t)(a0 + aa) * H_ + kc + kj];
        }
        __syncthreads();
#pragma unroll
        for (int kj = 0; kj < 32; ++kj) {
            float4 af0 = *(const float4*)&sA[kj][ty * 8];
            float4 af1 = *(const float4*)&sA[kj][ty * 8 + 4];
            float4 bf0 = *(const float4*)&sB[kj][tx * 8];
            float4 bf1 = *(const float4*)&sB[kj][tx * 8 + 4];
            float am[8] = {af0.x, af0.y, af0.z, af0.w, af1.x, af1.y, af1.z, af1.w};
            float bn[8] = {bf0.x, bf0.y, bf0.z, bf0.w, bf1.x, bf1.y, bf1.z, bf1.w};
#pragma unroll
            for (int i = 0; i < 8; ++i)
#pragma unroll
                for (int jj = 0; jj < 8; ++jj)
                    acc[i][jj] = fmaf(am[i], bn[jj], acc[i][jj]);
        }
        __syncthreads();
    }
#pragma unroll
    for (int i = 0; i < 8; ++i) {
        float* dst = proj + ((size_t)(b0 + ty * 8 + i) * S_ + s) * A_ + a0 + tx * 8;
        *(float4*)(dst) = make_float4(acc[i][0], acc[i][1], acc[i][2], acc[i][3]);
        *(float4*)(dst + 4) = make_float4(acc[i][4], acc[i][5], acc[i][6], acc[i][7]);
    }
}

__global__ void final_loss(const float* __restrict__ nlogp, float* __restrict__ out)
{
    __shared__ float part[C_];
    const int i = threadIdx.x; // 128
    float s = 0.f;
    for (int b = 0; b < B_; ++b) s += nlogp[(size_t)i * B_ + b];
    part[i] = s / (float)B_;
    __syncthreads();
    if (i == 0) {
        float t = 0.f;
        for (int k = 0; k < C_; ++k) t += part[k];
        out[0] = t / (float)B_ / (float)C_;
    }
}

extern "C" void kernel_launch(void* const* d_in, const int* in_sizes, int n_in,
                              void* d_out, int out_size, void* d_ws, size_t ws_size,
                              hipStream_t stream)
{
    (void)in_sizes; (void)n_in; (void)out_size; (void)ws_size;
    const float* x    = (const float*)d_in[0];
    const int*   y    = (const int*)d_in[1];
    const float* eWih = (const float*)d_in[2];
    const float* eWhh = (const float*)d_in[3];
    const float* ebih = (const float*)d_in[4];
    const float* ebhh = (const float*)d_in[5];
    const float* dWih = (const float*)d_in[6];
    const float* dWhh = (const float*)d_in[7];
    const float* dbih = (const float*)d_in[8];
    const float* dbhh = (const float*)d_in[9];
    const float* w1   = (const float*)d_in[10];
    const float* w2   = (const float*)d_in[11];
    const float* v    = (const float*)d_in[12];
    float* out = (float*)d_out;

    float* ws = (float*)d_ws;
    // Region A [0, 16,777,216): encT (slice 127 stays live through decode).
    float* encT    = ws;
    float* encT127 = ws + (size_t)127 * HSLICE;
    // Region B [16,777,216, 33,554,432): proj. Pre-proj: xT, W6e, h0T.
    float* projB  = ws + 16777216;
    float* xT     = projB;                    // 4,194,304
    float* W6e    = projB + 4194304;          // 983,040
    float* h0T    = projB + 5177344;          // 131,072
    // Region C beyond 33,554,432:
    float* C0     = ws + 33554432;
    float* bias4e = C0;                       // 2048
    float* bias4d = C0 + 2048;                // 2048
    float* nlogp  = C0 + 4096;                // 32,768
    float* hT0    = C0 + 36864;               // 131,072
    float* hT1    = C0 + 167936;              // 131,072
    float* hB     = C0 + 299008;              // 131,072
    float* w2qf   = C0 + 430080;              // 262,144
    float* W6d    = C0 + 692224;              // 983,040
    int*   predBuf = (int*)(C0 + 1675264);    // 256 ints

    // ---- prep (1 launch: both weight packs + transpose + biases) ----
    prep_all<<<dim3(3840), 256, 0, stream>>>(x, eWih, eWhh, dWih, dWhh,
                                             ebih, ebhh, dbih, dbhh, w2,
                                             xT, W6e, W6d, (float4*)w2qf,
                                             bias4e, bias4d, h0T);

    // ---- encoder: 128 launched steps ----
    for (int t = 0; t < S_; ++t) {
        const float* hin = (t == 0) ? h0T : encT + (size_t)(t - 1) * HSLICE;
        gru_step<<<dim3(512), 256, 0, stream>>>(
            xT + (size_t)t * (F_ * B_), nullptr, nullptr,
            hin, W6e, bias4e, encT + (size_t)t * HSLICE, nullptr);
    }

    // ---- proj ----
    proj_gemm<<<dim3(4, 2, 128), 256, 0, stream>>>(encT, w1, projB);

    // ---- decoder: 128 x 2 launched steps ----
    float* hb[2] = { hT0, hT1 };
    for (int st = 0; st < C_; ++st) {
        const float* hin = (st == 0) ? encT127 : hb[(st & 1) ^ 1];
        float* hout = hb[st & 1];
        gru_step<<<dim3(512), 256, 0, stream>>>(
            nullptr, x, (st > 0) ? predBuf : nullptr,
            hin, W6d, bias4d, hout, hB);
        w2attn_step<<<dim3(256), 512, 0, stream>>>(
            hB, (const float4*)w2qf, v, y, st, projB, predBuf, nlogp, out);
    }

    final_loss<<<dim3(1), 128, 0, stream>>>(nlogp, out + (size_t)B_ * C_);
}

// Round 17
// 7222.978 us; speedup vs baseline: 1.8221x; 1.8221x over previous
//
#include <hip/hip_runtime.h>
#include <math.h>

// Problem constants
#define B_ 256
#define S_ 128
#define F_ 128
#define H_ 512
#define A_ 512
#define C_ 128
#define HSLICE (H_ * B_)

#define DOT4(va, vb) ((va).x*(vb).x + (va).y*(vb).y + (va).z*(vb).z + (va).w*(vb).w)

// ---------------------------------------------------------------------------
// deep-prefetch k-major dot: 32-float double-buffer window.
// acc slots 0..3 = r0,r1,z0,z1 ; acc[NH],acc[NH+1] = n0,n1 partial.
// ---------------------------------------------------------------------------
template<int NH>
__device__ __forceinline__ void acc_chunks(const float* __restrict__ src,
                                           const float* __restrict__ W6k,
                                           int nk, int b, float* __restrict__ acc)
{
    float a0[32], a1[32];
#pragma unroll
    for (int j = 0; j < 32; ++j) a0[j] = src[(size_t)j * B_ + b];
    for (int kc = 0; kc < nk; kc += 32) {
        if (kc + 32 < nk) {
#pragma unroll
            for (int j = 0; j < 32; ++j)
                a1[j] = src[(size_t)(kc + 32 + j) * B_ + b];
        }
        const float* Wr = W6k + (size_t)kc * 6;
#pragma unroll
        for (int j = 0; j < 32; ++j) {
            float av = a0[j];
            acc[0]    = fmaf(av, Wr[j * 6 + 0], acc[0]);
            acc[1]    = fmaf(av, Wr[j * 6 + 1], acc[1]);
            acc[2]    = fmaf(av, Wr[j * 6 + 2], acc[2]);
            acc[3]    = fmaf(av, Wr[j * 6 + 3], acc[3]);
            acc[NH]   = fmaf(av, Wr[j * 6 + 4], acc[NH]);
            acc[NH+1] = fmaf(av, Wr[j * 6 + 5], acc[NH + 1]);
        }
#pragma unroll
        for (int j = 0; j < 32; ++j) a0[j] = a1[j];
    }
}

// per-lane x-row (128 contiguous floats) against W6 x-part; n -> slots 4,5
__device__ __forceinline__ void acc_xrow(const float4* __restrict__ xr,
                                         const float* __restrict__ W6k,
                                         float* __restrict__ acc)
{
    float4 c0[8], c1[8];
#pragma unroll
    for (int j = 0; j < 8; ++j) c0[j] = xr[j];
    for (int q = 0; q < 32; q += 8) {
        if (q + 8 < 32) {
#pragma unroll
            for (int j = 0; j < 8; ++j) c1[j] = xr[q + 8 + j];
        }
#pragma unroll
        for (int j = 0; j < 8; ++j) {
            const float* Wr = W6k + (size_t)((q + j) * 4) * 6;
            float e0 = c0[j].x, e1 = c0[j].y, e2 = c0[j].z, e3 = c0[j].w;
#pragma unroll
            for (int t2 = 0; t2 < 4; ++t2) {
                float av = (t2 == 0) ? e0 : (t2 == 1) ? e1 : (t2 == 2) ? e2 : e3;
                acc[0] = fmaf(av, Wr[t2 * 6 + 0], acc[0]);
                acc[1] = fmaf(av, Wr[t2 * 6 + 1], acc[1]);
                acc[2] = fmaf(av, Wr[t2 * 6 + 2], acc[2]);
                acc[3] = fmaf(av, Wr[t2 * 6 + 3], acc[3]);
                acc[4] = fmaf(av, Wr[t2 * 6 + 4], acc[4]);
                acc[5] = fmaf(av, Wr[t2 * 6 + 5], acc[5]);
            }
        }
#pragma unroll
        for (int j = 0; j < 8; ++j) c0[j] = c1[j];
    }
}

// ---------------------------------------------------------------------------
// prep_all: W6e + W6d + w2q packs, xT transpose, biases, h0T zero.
// grid 3840 x 256 (id < 983040).
// ---------------------------------------------------------------------------
__global__ __launch_bounds__(256)
void prep_all(const float* __restrict__ x,
              const float* __restrict__ eWih, const float* __restrict__ eWhh,
              const float* __restrict__ dWih, const float* __restrict__ dWhh,
              const float* __restrict__ ebih, const float* __restrict__ ebhh,
              const float* __restrict__ dbih, const float* __restrict__ dbhh,
              const float* __restrict__ w2,
              float* __restrict__ xT, float* __restrict__ W6e,
              float* __restrict__ W6d, float4* __restrict__ w2q,
              float* __restrict__ bias4e, float* __restrict__ bias4d,
              float* __restrict__ h0T)
{
    int id = blockIdx.x * 256 + threadIdx.x;   // < 983040
    {
        int up = id / 3840;
        int rem = id - up * 3840;
        int k = rem / 6, g = rem - k * 6;
        int row = (g >> 1) * H_ + up * 2 + (g & 1);
        if (k < F_) {
            W6e[id] = eWih[(size_t)row * F_ + k];
            W6d[id] = dWih[(size_t)row * F_ + k];
        } else {
            W6e[id] = eWhh[(size_t)row * H_ + (k - F_)];
            W6d[id] = dWhh[(size_t)row * H_ + (k - F_)];
        }
    }
#pragma unroll
    for (int r = 0; r < 5; ++r) {
        int xid = id + r * 983040;
        if (xid < S_ * F_ * B_) {
            int b2 = xid & 255, f = (xid >> 8) & 127, t = xid >> 15;
            xT[xid] = x[(size_t)b2 * (S_ * F_) + (size_t)t * F_ + f];
        }
    }
    if (id < 128 * 512) {
        int k4 = id >> 9, a = id & 511;
        const float* s = w2 + (size_t)a * H_ + k4 * 4;
        w2q[id] = make_float4(s[0], s[1], s[2], s[3]);
    }
    if (id < H_ * B_) h0T[id] = 0.f;
    if (id < H_) {
        bias4e[id * 4 + 0] = ebih[id] + ebhh[id];
        bias4e[id * 4 + 1] = ebih[H_ + id] + ebhh[H_ + id];
        bias4e[id * 4 + 2] = ebih[2 * H_ + id];
        bias4e[id * 4 + 3] = ebhh[2 * H_ + id];
        bias4d[id * 4 + 0] = dbih[id] + dbhh[id];
        bias4d[id * 4 + 1] = dbih[H_ + id] + dbhh[H_ + id];
        bias4d[id * 4 + 2] = dbih[2 * H_ + id];
        bias4d[id * 4 + 3] = dbhh[2 * H_ + id];
    }
}

// ---------------------------------------------------------------------------
// GRU step (round-14 validated geometry): grid 1024 = up(256) x bh(4),
// 128 threads = 2 waves (kw). Block owns unit-pair `up` x 64 batches.
// Many small independent blocks -> latency hiding via block-level TLP.
// ---------------------------------------------------------------------------
__global__ __launch_bounds__(128)
void gru_step(const float* __restrict__ inT,    // [F][B] k-major or nullptr
              const float* __restrict__ x,      // [B][S][F] or nullptr
              const int*   __restrict__ pred,   // [B] or nullptr
              const float* __restrict__ hinT,   // [H][B]
              const float* __restrict__ W6,     // [256][640][6]
              const float* __restrict__ bias4,  // [512][4]
              float* __restrict__ houtT,        // [H][B]
              float* __restrict__ hB)           // [B][H] or nullptr
{
    __shared__ float accL[64][6];
    const int tid = threadIdx.x;
    const int lane = tid & 63;
    const int kw = tid >> 6;
    const int up = blockIdx.x & 255;
    const int bh = blockIdx.x >> 8;
    const int b = bh * 64 + lane;
    const float* Wb = W6 + (size_t)up * 3840;
    const int u0 = up * 2, u1 = u0 + 1;

    float acc[8];
#pragma unroll
    for (int g = 0; g < 8; ++g) acc[g] = 0.f;

    float hold0 = 0.f, hold1 = 0.f;
    if (kw == 0) {
        hold0 = hinT[(size_t)u0 * B_ + b];
        hold1 = hinT[(size_t)u1 * B_ + b];
        if (inT) {
            acc_chunks<4>(inT, Wb, F_, b, acc);
        } else if (pred) {
            int pb = pred[b];
            const float4* xr = (const float4*)(x + ((size_t)b * S_ + pb) * F_);
            acc_xrow(xr, Wb, acc);
        }
        acc_chunks<6>(hinT, Wb + F_ * 6, 192, b, acc);
    } else {
        acc_chunks<6>(hinT + (size_t)192 * B_, Wb + 320 * 6, 320, b, acc);
    }

    if (kw == 1) {
        accL[lane][0] = acc[0]; accL[lane][1] = acc[1];
        accL[lane][2] = acc[2]; accL[lane][3] = acc[3];
        accL[lane][4] = acc[6]; accL[lane][5] = acc[7];
    }
    __syncthreads();
    if (kw == 0) {
        const float4 bb0 = *(const float4*)(bias4 + u0 * 4);
        const float4 bb1 = *(const float4*)(bias4 + u1 * 4);
        float rr0 = 1.f / (1.f + expf(-(acc[0] + accL[lane][0] + bb0.x)));
        float rr1 = 1.f / (1.f + expf(-(acc[1] + accL[lane][1] + bb1.x)));
        float zz0 = 1.f / (1.f + expf(-(acc[2] + accL[lane][2] + bb0.y)));
        float zz1 = 1.f / (1.f + expf(-(acc[3] + accL[lane][3] + bb1.y)));
        float hn0 = acc[6] + accL[lane][4] + bb0.w;
        float hn1 = acc[7] + accL[lane][5] + bb1.w;
        float nn0 = tanhf(acc[4] + bb0.z + rr0 * hn0);
        float nn1 = tanhf(acc[5] + bb1.z + rr1 * hn1);
        float h0v = (1.f - zz0) * nn0 + zz0 * hold0;
        float h1v = (1.f - zz1) * nn1 + zz1 * hold1;
        houtT[(size_t)u0 * B_ + b] = h0v;
        houtT[(size_t)u1 * B_ + b] = h1v;
        if (hB) {
            hB[(size_t)b * H_ + u0] = h0v;
            hB[(size_t)b * H_ + u1] = h1v;
        }
    }
}

// ---------------------------------------------------------------------------
// Fused w2 + attention + softmax + argmax + loss + pred publish.
// Block = batch b, 512 threads (8 waves). (round-14, validated)
// ---------------------------------------------------------------------------
__global__ __launch_bounds__(512)
void w2attn_step(const float* __restrict__ hB,    // [B][H]
                 const float4* __restrict__ w2q,  // [128 k4][512 a]
                 const float* __restrict__ v, const int* __restrict__ y,
                 int step, const float* __restrict__ proj,  // [b][s][a]
                 int* __restrict__ predBuf,
                 float* __restrict__ nlogp, float* __restrict__ preds_out)
{
    const int b = blockIdx.x;
    const int tid = threadIdx.x;
    __shared__ float sh[512];
    __shared__ float sq[512];
    __shared__ float sScore[S_], sProb[S_];

    sh[tid] = hB[(size_t)b * H_ + tid];
    __syncthreads();

    {
        float acc = 0.f;
        const float4* wp = w2q + tid;
#pragma unroll 8
        for (int k4 = 0; k4 < 128; ++k4) {
            float4 hv = *(const float4*)&sh[k4 * 4];
            float4 wv4 = wp[(size_t)k4 * 512];
            acc += DOT4(hv, wv4);
        }
        sq[tid] = acc;
    }
    __syncthreads();

    const int wv = tid >> 6, ln = tid & 63;
    float4 q0 = *(const float4*)&sq[ln * 8];
    float4 q1 = *(const float4*)&sq[ln * 8 + 4];
    float4 v0r = *(const float4*)(v + ln * 8);
    float4 v1r = *(const float4*)(v + ln * 8 + 4);
    const float* epb = proj + (size_t)b * (S_ * A_);
    for (int si = 0; si < 16; ++si) {
        int s = si * 8 + wv;
        const float* row = epb + (size_t)s * A_ + ln * 8;
        float4 p0 = *(const float4*)(row);
        float4 p1 = *(const float4*)(row + 4);
        float acc = fmaxf(p0.x + q0.x, 0.f) * v0r.x
                  + fmaxf(p0.y + q0.y, 0.f) * v0r.y
                  + fmaxf(p0.z + q0.z, 0.f) * v0r.z
                  + fmaxf(p0.w + q0.w, 0.f) * v0r.w
                  + fmaxf(p1.x + q1.x, 0.f) * v1r.x
                  + fmaxf(p1.y + q1.y, 0.f) * v1r.y
                  + fmaxf(p1.z + q1.z, 0.f) * v1r.z
                  + fmaxf(p1.w + q1.w, 0.f) * v1r.w;
#pragma unroll
        for (int off = 32; off; off >>= 1) acc += __shfl_down(acc, off);
        if (ln == 0) sScore[s] = acc;
    }
    __syncthreads();

    if (tid < 64) {
        float s0v = sScore[tid], s1v = sScore[tid + 64];
        float m = fmaxf(s0v, s1v);
#pragma unroll
        for (int off = 32; off; off >>= 1) m = fmaxf(m, __shfl_xor(m, off));
        float e0 = expf(s0v - m), e1 = expf(s1v - m);
        float se = e0 + e1;
#pragma unroll
        for (int off = 32; off; off >>= 1) se += __shfl_xor(se, off);
        float p0 = e0 / se, p1 = e1 / se;
        sProb[tid] = p0; sProb[tid + 64] = p1;
        float pm = fmaxf(p0, p1);
#pragma unroll
        for (int off = 32; off; off >>= 1) pm = fmaxf(pm, __shfl_xor(pm, off));
        float t0 = expf(p0 - pm), t1 = expf(p1 - pm);
        float T = t0 + t1;
#pragma unroll
        for (int off = 32; off; off >>= 1) T += __shfl_xor(T, off);
        float bv = p0; int bi2 = tid;
        if (p1 > bv) { bv = p1; bi2 = tid + 64; }
#pragma unroll
        for (int off = 32; off; off >>= 1) {
            float ov = __shfl_xor(bv, off);
            int oi = __shfl_xor(bi2, off);
            if (ov > bv || (ov == bv && oi < bi2)) { bv = ov; bi2 = oi; }
        }
        if (tid == 0) {
            int yy = y[(size_t)b * C_ + step];
            float py = sProb[yy];
            nlogp[(size_t)step * B_ + b] = -(py - pm - logf(T));
            preds_out[(size_t)b * C_ + step] = (float)bi2;
            predBuf[b] = bi2;
        }
    }
}

// ---------------------------------------------------------------------------
// proj[b][s][a] = sum_j encT[s][j][b] * w1[a][j]   (padded sB)
// ---------------------------------------------------------------------------
__global__ __launch_bounds__(256)
void proj_gemm(const float* __restrict__ encT, const float* __restrict__ w1,
               float* __restrict__ proj)
{
    __shared__ float sA[32][128];
    __shared__ float sB[32][132];
    const int tid = threadIdx.x;
    const int s = blockIdx.z;
    const int b0 = blockIdx.y * 128;
    const int a0 = blockIdx.x * 128;
    const int tx = tid & 15, ty = tid >> 4;

    float acc[8][8];
#pragma unroll
    for (int i = 0; i < 8; ++i)
#pragma unroll
        for (int jj = 0; jj < 8; ++jj) acc[i][jj] = 0.f;

    const float* Abase = encT + (size_t)s * HSLICE + b0;
    for (int kc = 0; kc < H_; kc += 32) {
#pragma unroll
        for (int p = 0; p < 16; ++p) {
            int idx = tid + p * 256;
            int kj = idx >> 7, bbb = idx & 127;
            sA[kj][bbb] = Abase[(size_t)(kc + kj) * B_ + bbb];
        }
#pragma unroll
        for (int p = 0; p < 16; ++p) {
            int idx = tid + p * 256;
            int aa = idx >> 5, kj = idx & 31;
            sB[kj][aa] = w1[(size_t)(a0 + aa) * H_ + kc + kj];
        }
        __syncthreads();
#pragma unroll
        for (int kj = 0; kj < 32; ++kj) {
            float4 af0 = *(const float4*)&sA[kj][ty * 8];
            float4 af1 = *(const float4*)&sA[kj][ty * 8 + 4];
            float4 bf0 = *(const float4*)&sB[kj][tx * 8];
            float4 bf1 = *(const float4*)&sB[kj][tx * 8 + 4];
            float am[8] = {af0.x, af0.y, af0.z, af0.w, af1.x, af1.y, af1.z, af1.w};
            float bn[8] = {bf0.x, bf0.y, bf0.z, bf0.w, bf1.x, bf1.y, bf1.z, bf1.w};
#pragma unroll
            for (int i = 0; i < 8; ++i)
#pragma unroll
                for (int jj = 0; jj < 8; ++jj)
                    acc[i][jj] = fmaf(am[i], bn[jj], acc[i][jj]);
        }
        __syncthreads();
    }
#pragma unroll
    for (int i = 0; i < 8; ++i) {
        float* dst = proj + ((size_t)(b0 + ty * 8 + i) * S_ + s) * A_ + a0 + tx * 8;
        *(float4*)(dst) = make_float4(acc[i][0], acc[i][1], acc[i][2], acc[i][3]);
        *(float4*)(dst + 4) = make_float4(acc[i][4], acc[i][5], acc[i][6], acc[i][7]);
    }
}

__global__ void final_loss(const float* __restrict__ nlogp, float* __restrict__ out)
{
    __shared__ float part[C_];
    const int i = threadIdx.x; // 128
    float s = 0.f;
    for (int b = 0; b < B_; ++b) s += nlogp[(size_t)i * B_ + b];
    part[i] = s / (float)B_;
    __syncthreads();
    if (i == 0) {
        float t = 0.f;
        for (int k = 0; k < C_; ++k) t += part[k];
        out[0] = t / (float)B_ / (float)C_;
    }
}

extern "C" void kernel_launch(void* const* d_in, const int* in_sizes, int n_in,
                              void* d_out, int out_size, void* d_ws, size_t ws_size,
                              hipStream_t stream)
{
    (void)in_sizes; (void)n_in; (void)out_size; (void)ws_size;
    const float* x    = (const float*)d_in[0];
    const int*   y    = (const int*)d_in[1];
    const float* eWih = (const float*)d_in[2];
    const float* eWhh = (const float*)d_in[3];
    const float* ebih = (const float*)d_in[4];
    const float* ebhh = (const float*)d_in[5];
    const float* dWih = (const float*)d_in[6];
    const float* dWhh = (const float*)d_in[7];
    const float* dbih = (const float*)d_in[8];
    const float* dbhh = (const float*)d_in[9];
    const float* w1   = (const float*)d_in[10];
    const float* w2   = (const float*)d_in[11];
    const float* v    = (const float*)d_in[12];
    float* out = (float*)d_out;

    float* ws = (float*)d_ws;
    // Region A [0, 16,777,216): encT (slice 127 stays live through decode).
    float* encT    = ws;
    float* encT127 = ws + (size_t)127 * HSLICE;
    // Region B [16,777,216, 33,554,432): proj. Pre-proj: xT, W6e, h0T.
    float* projB  = ws + 16777216;
    float* xT     = projB;                    // 4,194,304
    float* W6e    = projB + 4194304;          // 983,040
    float* h0T    = projB + 5177344;          // 131,072
    // Region C beyond 33,554,432:
    float* C0     = ws + 33554432;
    float* bias4e = C0;                       // 2048
    float* bias4d = C0 + 2048;                // 2048
    float* nlogp  = C0 + 4096;                // 32,768
    float* hT0    = C0 + 36864;               // 131,072
    float* hT1    = C0 + 167936;              // 131,072
    float* hB     = C0 + 299008;              // 131,072
    float* w2qf   = C0 + 430080;              // 262,144
    float* W6d    = C0 + 692224;              // 983,040
    int*   predBuf = (int*)(C0 + 1675264);    // 256 ints

    // ---- prep (1 launch: both weight packs + transpose + biases) ----
    prep_all<<<dim3(3840), 256, 0, stream>>>(x, eWih, eWhh, dWih, dWhh,
                                             ebih, ebhh, dbih, dbhh, w2,
                                             xT, W6e, W6d, (float4*)w2qf,
                                             bias4e, bias4d, h0T);

    // ---- encoder: 128 launched steps ----
    for (int t = 0; t < S_; ++t) {
        const float* hin = (t == 0) ? h0T : encT + (size_t)(t - 1) * HSLICE;
        gru_step<<<dim3(1024), 128, 0, stream>>>(
            xT + (size_t)t * (F_ * B_), nullptr, nullptr,
            hin, W6e, bias4e, encT + (size_t)t * HSLICE, nullptr);
    }

    // ---- proj ----
    proj_gemm<<<dim3(4, 2, 128), 256, 0, stream>>>(encT, w1, projB);

    // ---- decoder: 128 x 2 launched steps ----
    float* hb[2] = { hT0, hT1 };
    for (int st = 0; st < C_; ++st) {
        const float* hin = (st == 0) ? encT127 : hb[(st & 1) ^ 1];
        float* hout = hb[st & 1];
        gru_step<<<dim3(1024), 128, 0, stream>>>(
            nullptr, x, (st > 0) ? predBuf : nullptr,
            hin, W6d, bias4d, hout, hB);
        w2attn_step<<<dim3(256), 512, 0, stream>>>(
            hB, (const float4*)w2qf, v, y, st, projB, predBuf, nlogp, out);
    }

    final_loss<<<dim3(1), 128, 0, stream>>>(nlogp, out + (size_t)B_ * C_);
}